// Round 7
// baseline (1631.136 us; speedup 1.0000x reference)
//
#include <hip/hip_runtime.h>
#include <cstdint>

#define NN0 80000
#define NE 1280000
#define EB 2048          // elems per block in edge bucket pass (NE/EB = 625 exact)
#define ENB 625
#define RD 2048          // radix bins (11-bit digits)
#define RDM 2047

static inline int cdiv(int a, int b){ return (a+b-1)/b; }

// ======================= edge bucket pass (6-bit digit @ shift=11) =======================
// also zeroes indeg (needed by escatter6's embedded degree count, 2 dispatches later)
__global__ void k_ehist6(const int* __restrict__ key, int* __restrict__ hist, int shift,
                         int* __restrict__ indeg){
  for (int i = blockIdx.x*blockDim.x + threadIdx.x; i < NN0; i += gridDim.x*blockDim.x)
    indeg[i] = 0;
  __shared__ int lh[64];
  if (threadIdx.x < 64) lh[threadIdx.x] = 0;
  __syncthreads();
  int base = blockIdx.x*EB + threadIdx.x;
  #pragma unroll
  for (int u = 0; u < 8; u++)
    atomicAdd(&lh[(key[base + u*256] >> shift) & 63], 1);
  __syncthreads();
  if (threadIdx.x < 64) hist[threadIdx.x*ENB + blockIdx.x] = lh[threadIdx.x];
}

__global__ void k_scan_part(const int* __restrict__ in, int* __restrict__ bsum, int n){
  __shared__ int ws[256];
  int base = blockIdx.x*2048 + threadIdx.x*8;
  int s = 0;
  #pragma unroll
  for (int u = 0; u < 8; u++){ int i = base+u; if (i < n) s += in[i]; }
  ws[threadIdx.x] = s; __syncthreads();
  for (int st = 128; st > 0; st >>= 1){
    if (threadIdx.x < st) ws[threadIdx.x] += ws[threadIdx.x+st];
    __syncthreads();
  }
  if (threadIdx.x == 0) bsum[blockIdx.x] = ws[0];
}

__global__ void k_scan_fin_flat(int* __restrict__ data, const int* __restrict__ bsum, int nb, int n){
  __shared__ int bws[256]; __shared__ int ws[256];
  int t = threadIdx.x;
  bws[t] = (t < nb) ? bsum[t] : 0; __syncthreads();
  for (int st = 1; st < 256; st <<= 1){
    int a = (t >= st) ? bws[t-st] : 0; __syncthreads();
    bws[t] += a; __syncthreads();
  }
  int blockoff = (blockIdx.x == 0) ? 0 : bws[blockIdx.x-1];
  int base = blockIdx.x*2048 + t*8;
  int v[8]; int s = 0;
  #pragma unroll
  for (int u = 0; u < 8; u++){ int i = base+u; v[u] = (i < n) ? data[i] : 0; s += v[u]; }
  ws[t] = s; __syncthreads();
  for (int st = 1; st < 256; st <<= 1){
    int a = (t >= st) ? ws[t-st] : 0; __syncthreads();
    ws[t] += a; __syncthreads();
  }
  int off = blockoff + ws[t] - s;
  #pragma unroll
  for (int u = 0; u < 8; u++){
    int i = base+u;
    if (i < n){ data[i] = off; off += v[u]; }
  }
}

// bucket scatter + embedded degree count (random-target atomics — proven cheap in r5)
__global__ void k_escatter6(const int* __restrict__ keyin, const int* __restrict__ valin,
                            int* __restrict__ keyout, int* __restrict__ valout,
                            const int* __restrict__ hist, int shift,
                            int* __restrict__ indeg){
  __shared__ int dbase[64], run[64], wcnt[4][64];
  int t = threadIdx.x, lane = t & 63, w = t >> 6;
  if (t < 64){ dbase[t] = hist[t*ENB + blockIdx.x]; run[t] = 0; }
  __syncthreads();
  for (int u = 0; u < 8; u++){
    if (t < 64){ wcnt[0][t]=0; wcnt[1][t]=0; wcnt[2][t]=0; wcnt[3][t]=0; }
    __syncthreads();
    int g = blockIdx.x*EB + u*256 + t;
    int kk = keyin[g], vv = valin[g];
    int d = (kk >> shift) & 63;
    unsigned long long m = ~0ull;
    #pragma unroll
    for (int b = 0; b < 6; b++){
      unsigned long long bal = __ballot((d >> b) & 1);
      m &= ((d >> b) & 1) ? bal : ~bal;
    }
    int rnk = __popcll(m & ((1ull << lane) - 1ull));
    if (rnk == 0) wcnt[w][d] = __popcll(m);
    __syncthreads();
    int off2 = run[d] + rnk;
    for (int w2 = 0; w2 < w; w2++) off2 += wcnt[w2][d];
    int pos = dbase[d] + off2;
    keyout[pos] = kk; valout[pos] = vv;
    atomicAdd(&indeg[kk], 1);
    __syncthreads();
    if (t < 64) run[t] += wcnt[0][t] + wcnt[1][t] + wcnt[2][t] + wcnt[3][t];
    __syncthreads();
  }
}

// col scatter from bucketed edges: cursor atomics + writes stay in per-bucket windows
__global__ void k_escat_local(const int* __restrict__ ek, const int* __restrict__ ev,
                              int* __restrict__ cur, int* __restrict__ col){
  for (int e = blockIdx.x*blockDim.x + threadIdx.x; e < NE; e += gridDim.x*blockDim.x){
    int d = ek[e];
    int pos = atomicAdd(&cur[d], 1);
    col[pos] = ev[e];
  }
}

// ======================= fused single-dispatch scan =======================
__global__ void k_scan_rp(const int* __restrict__ in, int* __restrict__ rp,
                          int* __restrict__ cur, float* __restrict__ dA,
                          float* __restrict__ dB, int n){
  __shared__ int ws[256];
  int t = threadIdx.x;
  int pre = blockIdx.x*2048;
  int s = 0;
  for (int i = t; i < pre; i += 256) s += in[i];
  ws[t] = s; __syncthreads();
  for (int st = 128; st > 0; st >>= 1){
    if (t < st) ws[t] += ws[t+st];
    __syncthreads();
  }
  int blockoff = ws[0];
  __syncthreads();
  int base = pre + t*8;
  int v[8]; int ls = 0;
  #pragma unroll
  for (int u = 0; u < 8; u++){ int i = base+u; v[u] = (i < n) ? in[i] : 0; ls += v[u]; }
  ws[t] = ls; __syncthreads();
  for (int st = 1; st < 256; st <<= 1){
    int a = (t >= st) ? ws[t-st] : 0; __syncthreads();
    ws[t] += a; __syncthreads();
  }
  int off = blockoff + ws[t] - ls;
  #pragma unroll
  for (int u = 0; u < 8; u++){
    int i = base+u;
    if (i < n){
      rp[i] = off;
      if (cur) cur[i] = off;
      off += v[u];
      dA[i] = 1.0f/sqrtf((float)v[u] + 2.f);
      if (dB) dB[i] = 1.0f/sqrtf((float)v[u] + 1.f);
      if (i == n-1) rp[n] = off;
    }
  }
}

// ======================= convs (gather + matmul + BN partials) =======================
__global__ void k_conv64(const int* __restrict__ rp, const int* __restrict__ col,
                         const float* __restrict__ dinv, const float* __restrict__ x,
                         const float* __restrict__ W, float* __restrict__ out,
                         float* __restrict__ part, int n){
  __shared__ float yl[4][64];
  __shared__ float ls[64], lq[64];
  int lane = threadIdx.x & 63, w = threadIdx.x >> 6;
  if (threadIdx.x < 64){ ls[threadIdx.x] = 0.f; lq[threadIdx.x] = 0.f; }
  __syncthreads();
  float sa = 0.f, sq = 0.f;
  int wid = blockIdx.x*4 + w, nw = gridDim.x*4;
  for (int i = wid; i < n; i += nw){
    int beg = rp[i], end = rp[i+1];
    float di = dinv[i];
    float y = 0.f;
    int j = beg;
    for (; j + 4 <= end; j += 4){
      int s0 = col[j], s1 = col[j+1], s2 = col[j+2], s3 = col[j+3];
      float y0 = dinv[s0]*x[s0*64+lane];
      float y1 = dinv[s1]*x[s1*64+lane];
      float y2 = dinv[s2]*x[s2*64+lane];
      float y3 = dinv[s3]*x[s3*64+lane];
      y += (y0+y1) + (y2+y3);
    }
    for (; j < end; j++){ int s = col[j]; y += dinv[s]*x[s*64+lane]; }
    y = di*y + 2.f*di*di*x[i*64+lane];
    yl[w][lane] = y;
    float acc = 0.f;
    #pragma unroll
    for (int k2 = 0; k2 < 64; k2++)
      acc += yl[w][k2]*W[k2*64+lane];
    out[i*64+lane] = acc;
    sa += acc; sq += acc*acc;
  }
  atomicAdd(&ls[lane], sa); atomicAdd(&lq[lane], sq);
  __syncthreads();
  if (threadIdx.x < 128)
    part[blockIdx.x*128 + threadIdx.x] =
      (threadIdx.x < 64) ? ls[threadIdx.x] : lq[threadIdx.x-64];
}

__global__ void k_conv3(const int* __restrict__ rp, const int* __restrict__ col,
                        const float* __restrict__ dinv, const float* __restrict__ x,
                        const float* __restrict__ W, float* __restrict__ out,
                        float* __restrict__ part, int n){
  __shared__ float ls[64], lq[64];
  int lane = threadIdx.x & 63, w = threadIdx.x >> 6;
  if (threadIdx.x < 64){ ls[threadIdx.x] = 0.f; lq[threadIdx.x] = 0.f; }
  __syncthreads();
  float wf0 = W[lane], wf1 = W[64+lane], wf2 = W[128+lane];
  float sa = 0.f, sq = 0.f;
  int wid = blockIdx.x*4 + w, nw = gridDim.x*4;
  for (int i = wid; i < n; i += nw){
    int beg = rp[i], end = rp[i+1];
    float a0 = 0.f, a1 = 0.f, a2 = 0.f;
    for (int j = beg + lane; j < end; j += 64){
      int s2 = col[j];
      float ds = dinv[s2];
      a0 += ds*x[s2*3+0]; a1 += ds*x[s2*3+1]; a2 += ds*x[s2*3+2];
    }
    for (int o = 32; o > 0; o >>= 1){
      a0 += __shfl_xor(a0, o); a1 += __shfl_xor(a1, o); a2 += __shfl_xor(a2, o);
    }
    float di = dinv[i];
    float sl = 2.f*di*di;
    a0 = di*a0 + sl*x[i*3+0];
    a1 = di*a1 + sl*x[i*3+1];
    a2 = di*a2 + sl*x[i*3+2];
    float s = a0*wf0 + a1*wf1 + a2*wf2;
    out[i*64+lane] = s; sa += s; sq += s*s;
  }
  atomicAdd(&ls[lane], sa); atomicAdd(&lq[lane], sq);
  __syncthreads();
  if (threadIdx.x < 128)
    part[blockIdx.x*128 + threadIdx.x] =
      (threadIdx.x < 64) ? ls[threadIdx.x] : lq[threadIdx.x-64];
}

__global__ void k_stats_reduce(const float* __restrict__ part, float* __restrict__ stats, int nb){
  int c = blockIdx.x, lane = threadIdx.x;
  float s = 0.f;
  for (int b = lane; b < nb; b += 64) s += part[b*128 + c];
  for (int o = 32; o > 0; o >>= 1) s += __shfl_xor(s, o);
  if (lane == 0) stats[c] = s;
}

// ======== pool: BN+ReLU (in-place) + score + key init + pass-0 hist (11-bit) ========
// blocked node assignment: block b handles nodes [b*1024,(b+1)*1024) so the LDS
// histogram is exactly the per-1024-block pass-0 hist the scatter expects.
__global__ void k_bnrelu_score(float* __restrict__ x, const float* __restrict__ stats,
                               const float* __restrict__ gamma, const float* __restrict__ beta,
                               const float* __restrict__ pw,
                               float* __restrict__ score, unsigned* __restrict__ key,
                               int* __restrict__ idx, int* __restrict__ hist,
                               int n, int nblk){
  __shared__ int lh[RD];
  int t = threadIdx.x, lane = t & 63, w = t >> 6;
  #pragma unroll
  for (int j = 0; j < 8; j++) lh[t*8+j] = 0;
  float inv_n = 1.f/(float)n;
  float mu = stats[lane]*inv_n;
  float var = stats[64+lane]*inv_n - mu*mu;
  float gs = gamma[lane]*(1.f/sqrtf(var+1e-5f));
  float bt = beta[lane];
  float pv = pw[lane];
  float q = pv*pv;
  for (int o = 32; o > 0; o >>= 1) q += __shfl_xor(q, o);
  float qn = 1.f/sqrtf(q);
  __syncthreads();
  int P = nblk*1024;
  int base = blockIdx.x*1024 + w*256;
  for (int t2 = 0; t2 < 256; t2++){
    int i = base + t2;
    if (i < n){
      float v = fmaxf(gs*(x[i*64+lane]-mu)+bt, 0.f);
      x[i*64+lane] = v;
      float s = v*pv;
      for (int o = 32; o > 0; o >>= 1) s += __shfl_xor(s, o);
      if (lane == 0){
        float sc = fmaxf(s*qn, 0.f);
        unsigned kk = ~__float_as_uint(sc);
        score[i] = sc; key[i] = kk; idx[i] = i;
        atomicAdd(&lh[kk & RDM], 1);
      }
    } else if (i < P){
      if (lane == 0){
        key[i] = 0xFFFFFFFFu; idx[i] = 0;
        atomicAdd(&lh[RDM], 1);
      }
    }
  }
  __syncthreads();
  #pragma unroll
  for (int j = 0; j < 8; j++)
    hist[(t*8+j)*nblk + blockIdx.x] = lh[t*8+j];
}

// 11-bit histogram for passes 1,2
__global__ void k_radix_hist11(const unsigned* __restrict__ key, int* __restrict__ hist,
                               int shift, int nblk){
  __shared__ int lh[RD];
  int t = threadIdx.x;
  #pragma unroll
  for (int j = 0; j < 8; j++) lh[t*8+j] = 0;
  __syncthreads();
  int base = blockIdx.x*1024 + t;
  #pragma unroll
  for (int u = 0; u < 4; u++)
    atomicAdd(&lh[(key[base + u*256] >> shift) & RDM], 1);
  __syncthreads();
  #pragma unroll
  for (int j = 0; j < 8; j++)
    hist[(t*8+j)*nblk + blockIdx.x] = lh[t*8+j];
}

// 11-bit stable scatter; fin=1 (last pass) writes perm/mapv/xk directly.
__global__ void k_radix_scatter11(const unsigned* __restrict__ keyin, const int* __restrict__ idxin,
                                  unsigned* __restrict__ keyout, int* __restrict__ idxout,
                                  const int* __restrict__ hist, int shift, int nblk,
                                  int fin, const float* __restrict__ x,
                                  const float* __restrict__ score,
                                  int* __restrict__ perm, int* __restrict__ mapv,
                                  float* __restrict__ xk, int n, int k){
  __shared__ int dbase[RD], run[RD], wcnt[4][RD];
  __shared__ int ssum[256], stmp[256];
  int t = threadIdx.x, lane = t & 63, w = t >> 6;
  int b = blockIdx.x;
  int pre[8], tot[8];
  #pragma unroll
  for (int j = 0; j < 8; j++){ pre[j] = 0; tot[j] = 0; }
  for (int blk = 0; blk < nblk; blk++){
    #pragma unroll
    for (int j = 0; j < 8; j++){
      int v = hist[(t*8+j)*nblk + blk];
      tot[j] += v;
      if (blk < b) pre[j] += v;
    }
  }
  int S = 0; int ex[8];
  #pragma unroll
  for (int j = 0; j < 8; j++){ ex[j] = S; S += tot[j]; }
  ssum[t] = S; __syncthreads();
  int* cu = ssum; int* ot = stmp;
  for (int st = 1; st < 256; st <<= 1){
    ot[t] = cu[t] + ((t >= st) ? cu[t-st] : 0);
    __syncthreads();
    int* tmp = cu; cu = ot; ot = tmp;
  }
  int exS = cu[t] - S;
  #pragma unroll
  for (int j = 0; j < 8; j++){
    dbase[t*8+j] = exS + ex[j] + pre[j];
    run[t*8+j] = 0;
  }
  __syncthreads();
  for (int u = 0; u < 4; u++){
    #pragma unroll
    for (int j = 0; j < 8; j++){
      int bb = t*8+j;
      wcnt[0][bb] = 0; wcnt[1][bb] = 0; wcnt[2][bb] = 0; wcnt[3][bb] = 0;
    }
    __syncthreads();
    int g = b*1024 + u*256 + t;
    unsigned kk = keyin[g]; int id = idxin[g];
    int d = (kk >> shift) & RDM;
    unsigned long long m = ~0ull;
    #pragma unroll
    for (int bit = 0; bit < 11; bit++){
      unsigned long long bal = __ballot((d >> bit) & 1);
      m &= ((d >> bit) & 1) ? bal : ~bal;
    }
    int rnk = __popcll(m & ((1ull << lane) - 1ull));
    if (rnk == 0) wcnt[w][d] = __popcll(m);
    __syncthreads();
    int off2 = run[d] + rnk;
    for (int w2 = 0; w2 < w; w2++) off2 += wcnt[w2][d];
    int pos = dbase[d] + off2;
    if (!fin){
      keyout[pos] = kk; idxout[pos] = id;
    } else if (pos < n){
      mapv[id] = (pos < k) ? pos : -1;
      if (pos < k){
        perm[pos] = id;
        float sc = score[id];
        const float4* xr = (const float4*)(x + (size_t)id*64);
        float4* xo = (float4*)(xk + (size_t)pos*64);
        #pragma unroll
        for (int f = 0; f < 16; f++){
          float4 vv = xr[f];
          vv.x *= sc; vv.y *= sc; vv.z *= sc; vv.w *= sc;
          xo[f] = vv;
        }
      }
    }
    __syncthreads();
    #pragma unroll
    for (int j = 0; j < 8; j++){
      int bb = t*8+j;
      run[bb] += wcnt[0][bb] + wcnt[1][bb] + wcnt[2][bb] + wcnt[3][bb];
    }
    __syncthreads();
  }
}

// ======================= child CSR from parent CSR + injective mapping ================
__global__ void k_hist_mapped(const int* __restrict__ rp_p, const int* __restrict__ col_p,
                              const int* __restrict__ mapv, int* __restrict__ indeg, int np){
  int d = blockIdx.x*blockDim.x + threadIdx.x;
  if (d >= np) return;
  int md = mapv[d];
  if (md < 0) return;
  int c = 0, e = rp_p[d+1];
  int j = rp_p[d];
  for (; j + 4 <= e; j += 4){
    int c0 = (mapv[col_p[j]]   >= 0);
    int c1 = (mapv[col_p[j+1]] >= 0);
    int c2 = (mapv[col_p[j+2]] >= 0);
    int c3 = (mapv[col_p[j+3]] >= 0);
    c += (c0+c1) + (c2+c3);
  }
  for (; j < e; j++) if (mapv[col_p[j]] >= 0) c++;
  indeg[md] = c;
}

__global__ void k_scatter_mapped(const int* __restrict__ rp_p, const int* __restrict__ col_p,
                                 const int* __restrict__ mapv, const int* __restrict__ rp_c,
                                 int* __restrict__ col_c, int np){
  int d = blockIdx.x*blockDim.x + threadIdx.x;
  if (d >= np) return;
  int md = mapv[d];
  if (md < 0) return;
  int pos = rp_c[md], e = rp_p[d+1];
  int j = rp_p[d];
  for (; j + 4 <= e; j += 4){
    int m0 = mapv[col_p[j]], m1 = mapv[col_p[j+1]];
    int m2 = mapv[col_p[j+2]], m3 = mapv[col_p[j+3]];
    if (m0 >= 0) col_c[pos++] = m0;
    if (m1 >= 0) col_c[pos++] = m1;
    if (m2 >= 0) col_c[pos++] = m2;
    if (m3 >= 0) col_c[pos++] = m3;
  }
  for (; j < e; j++){
    int ms = mapv[col_p[j]];
    if (ms >= 0) col_c[pos++] = ms;
  }
}

// ======================= up-path BN+ReLU + scatter-add =======================
__global__ void k_bnrelu_scatter(const float* __restrict__ x, const float* __restrict__ stats,
                                 const float* __restrict__ gamma, const float* __restrict__ beta,
                                 const int* __restrict__ perm, float* __restrict__ res, int n){
  int t = blockIdx.x*blockDim.x + threadIdx.x;
  if (t >= n*64) return;
  int r = t >> 6, f = t & 63;
  float inv_n = 1.0f/(float)n;
  float mu = stats[f]*inv_n;
  float var = stats[64+f]*inv_n - mu*mu;
  float v = gamma[f]*(x[t]-mu)*(1.0f/sqrtf(var+1e-5f)) + beta[f];
  res[perm[r]*64+f] += fmaxf(v, 0.f);
}

// ======================= final conv =======================
__global__ void k_matvec(const float* __restrict__ x, const float* __restrict__ W,
                         float* __restrict__ h1, int n){
  int lane = threadIdx.x & 63, w = threadIdx.x >> 6;
  int wid = blockIdx.x*4 + w, nw = gridDim.x*4;
  float wv = W[lane];
  for (int i = wid; i < n; i += nw){
    float v = x[i*64+lane]*wv;
    for (int o = 32; o > 0; o >>= 1) v += __shfl_xor(v, o);
    if (lane == 0) h1[i] = v;
  }
}

__global__ void k_gather_sig(const int* __restrict__ rp, const int* __restrict__ col,
                             const float* __restrict__ dinv, const float* __restrict__ h1,
                             float* __restrict__ out, int n){
  int i = blockIdx.x*blockDim.x + threadIdx.x;
  if (i >= n) return;
  int beg = rp[i], end = rp[i+1];
  float di = dinv[i];
  float acc = 0.f;
  int j = beg;
  for (; j + 4 <= end; j += 4){
    int s0 = col[j], s1 = col[j+1], s2 = col[j+2], s3 = col[j+3];
    float v0 = dinv[s0]*h1[s0];
    float v1 = dinv[s1]*h1[s1];
    float v2 = dinv[s2]*h1[s2];
    float v3 = dinv[s3]*h1[s3];
    acc += (v0+v1) + (v2+v3);
  }
  for (; j < end; j++) acc += dinv[col[j]]*h1[col[j]];
  float v = di*acc + di*di*h1[i];
  out[i] = 1.f/(1.f+expf(-v));
}

// ======================= host =======================

extern "C" void kernel_launch(void* const* d_in, const int* in_sizes, int n_in,
                              void* d_out, int out_size, void* d_ws, size_t ws_size,
                              hipStream_t stream) {
  const float* x_in = (const float*)d_in[0];
  const int* ei = (const int*)d_in[1];
  const int* src0 = ei;
  const int* dst0 = ei + NE;
  const float* W_d[4] = {(const float*)d_in[2],(const float*)d_in[5],(const float*)d_in[8],(const float*)d_in[11]};
  const float* g_d[4] = {(const float*)d_in[3],(const float*)d_in[6],(const float*)d_in[9],(const float*)d_in[12]};
  const float* b_d[4] = {(const float*)d_in[4],(const float*)d_in[7],(const float*)d_in[10],(const float*)d_in[13]};
  const float* pw[3]  = {(const float*)d_in[14],(const float*)d_in[15],(const float*)d_in[16]};
  const float* W_u[2] = {(const float*)d_in[17],(const float*)d_in[20]};
  const float* g_u[2] = {(const float*)d_in[18],(const float*)d_in[21]};
  const float* b_u[2] = {(const float*)d_in[19],(const float*)d_in[22]};
  const float* W_out  = (const float*)d_in[23];
  float* out = (float*)d_out;

  float* base = (float*)d_ws;
  size_t off = 0;
  auto alloc = [&](size_t nf){ float* p = base + off; off += nf; return p; };
  float* x0 = alloc(5120000);
  float* x1 = alloc(2560000);
  float* x2 = alloc(1280000);
  float* x3 = alloc(640000);
  float* A  = alloc(2560000);
  int* col0 = (int*)alloc(NE);
  int* col1 = (int*)alloc(NE);
  int* col2 = (int*)alloc(NE);
  int* col3 = (int*)alloc(NE);
  int* ek1 = (int*)alloc(NE);
  int* ev1 = (int*)alloc(NE);
  int* rp0 = (int*)alloc(80001);
  int* rp1 = (int*)alloc(40001);
  int* rp2 = (int*)alloc(20001);
  int* rp3 = (int*)alloc(10001);
  int* cur0 = (int*)alloc(NN0);
  int* indeg  = (int*)alloc(NN0);
  float* dinv0  = alloc(NN0);
  float* dinv0f = alloc(NN0);
  float* dinv1  = alloc(40000);
  float* dinv2  = alloc(20000);
  float* dinv3  = alloc(10000);
  float* score = alloc(NN0);
  int* mapv = (int*)alloc(NN0);
  int* p0 = (int*)alloc(40000);
  int* p1 = (int*)alloc(20000);
  int* p2 = (int*)alloc(10000);
  float* stats = alloc(128);
  float* part  = alloc(2048*128);
  unsigned* keyA = (unsigned*)alloc(81920);
  unsigned* keyB = (unsigned*)alloc(81920);
  int* idxA = (int*)alloc(81920);
  int* idxB = (int*)alloc(81920);
  int* hist = (int*)alloc(RD*80);      // 2048 bins x up to 79 blocks
  int* ehist = (int*)alloc(64*ENB);
  int* bsum = (int*)alloc(256);
  (void)ws_size; (void)in_sizes; (void)n_in; (void)out_size;

  const int B = 256;

  // ---- level-0 CSR: bucket scatter (+deg) + fused scan + local col scatter ----
  k_ehist6<<<ENB, B, 0, stream>>>(dst0, ehist, 11, indeg);
  {
    int nb = cdiv(64*ENB, 2048);
    k_scan_part    <<<nb, B, 0, stream>>>(ehist, bsum, 64*ENB);
    k_scan_fin_flat<<<nb, B, 0, stream>>>(ehist, bsum, nb, 64*ENB);
  }
  k_escatter6<<<ENB, B, 0, stream>>>(dst0, src0, ek1, ev1, ehist, 11, indeg);
  k_scan_rp<<<cdiv(NN0,2048), B, 0, stream>>>(indeg, rp0, cur0, dinv0, dinv0f, NN0);
  k_escat_local<<<1024, B, 0, stream>>>(ek1, ev1, cur0, col0);

  auto conv = [&](const float* xin, const float* W, int n, int nb,
                  const int* rp, const int* col, const float* dv, float* dstb){
    k_conv64<<<nb, B, 0, stream>>>(rp, col, dv, xin, W, dstb, part, n);
    k_stats_reduce<<<128, 64, 0, stream>>>(part, stats, nb);
  };

  auto pool = [&](float* xb, const float* gm, const float* bt, const float* pwv,
                  int n, int k, int* pm){
    int nblk = cdiv(n, 1024);
    k_bnrelu_score<<<nblk, B, 0, stream>>>(xb, stats, gm, bt, pwv, score, keyA, idxA,
                                           hist, n, nblk);
    k_radix_scatter11<<<nblk, B, 0, stream>>>(keyA, idxA, keyB, idxB, hist, 0, nblk,
                                              0, nullptr, nullptr, nullptr, nullptr, nullptr, n, k);
    k_radix_hist11<<<nblk, B, 0, stream>>>(keyB, hist, 11, nblk);
    k_radix_scatter11<<<nblk, B, 0, stream>>>(keyB, idxB, keyA, idxA, hist, 11, nblk,
                                              0, nullptr, nullptr, nullptr, nullptr, nullptr, n, k);
    k_radix_hist11<<<nblk, B, 0, stream>>>(keyA, hist, 22, nblk);
    k_radix_scatter11<<<nblk, B, 0, stream>>>(keyA, idxA, keyB, idxB, hist, 22, nblk,
                                              1, xb, score, pm, mapv, A, n, k);
  };

  auto csr_mapped = [&](const int* rp_p, const int* col_p, int np, int nc,
                        int* rp_c, int* col_c, float* dv){
    k_hist_mapped<<<cdiv(np,B), B, 0, stream>>>(rp_p, col_p, mapv, indeg, np);
    k_scan_rp<<<cdiv(nc,2048), B, 0, stream>>>(indeg, rp_c, nullptr, dv, nullptr, nc);
    k_scatter_mapped<<<cdiv(np,B), B, 0, stream>>>(rp_p, col_p, mapv, rp_c, col_c, np);
  };

  // ---- down path ----
  k_conv3<<<2048, B, 0, stream>>>(rp0, col0, dinv0, x_in, W_d[0], x0, part, NN0);
  k_stats_reduce<<<128, 64, 0, stream>>>(part, stats, 2048);
  pool(x0, g_d[0], b_d[0], pw[0], NN0, 40000, p0);
  csr_mapped(rp0, col0, NN0, 40000, rp1, col1, dinv1);

  conv(A, W_d[1], 40000, 2048, rp1, col1, dinv1, x1);
  pool(x1, g_d[1], b_d[1], pw[1], 40000, 20000, p1);
  csr_mapped(rp1, col1, 40000, 20000, rp2, col2, dinv2);

  conv(A, W_d[2], 20000, 1024, rp2, col2, dinv2, x2);
  pool(x2, g_d[2], b_d[2], pw[2], 20000, 10000, p2);
  csr_mapped(rp2, col2, 20000, 10000, rp3, col3, dinv3);

  conv(A, W_d[3], 10000, 512, rp3, col3, dinv3, x3);

  // ---- up path (BN+ReLU fused into the skip-connection scatter-add) ----
  k_bnrelu_scatter<<<cdiv(10000*64,B), B, 0, stream>>>(x3, stats, g_d[3], b_d[3], p2, x2, 10000);
  conv(x2, W_u[0], 20000, 1024, rp2, col2, dinv2, A);
  k_bnrelu_scatter<<<cdiv(20000*64,B), B, 0, stream>>>(A, stats, g_u[0], b_u[0], p1, x1, 20000);
  conv(x1, W_u[1], 40000, 2048, rp1, col1, dinv1, A);
  k_bnrelu_scatter<<<cdiv(40000*64,B), B, 0, stream>>>(A, stats, g_u[1], b_u[1], p0, x0, 40000);

  // ---- final conv (fill = 1.0) fused with sigmoid ----
  float* h1 = score;  // reuse
  k_matvec<<<512, B, 0, stream>>>(x0, W_out, h1, NN0);
  k_gather_sig<<<cdiv(NN0,B), B, 0, stream>>>(rp0, col0, dinv0f, h1, out, NN0);
}

// Round 8
// 861.335 us; speedup vs baseline: 1.8937x; 1.8937x over previous
//
#include <hip/hip_runtime.h>
#include <cstdint>

#define NN0 80000
#define NE 1280000
#define EB 2048          // elems per block in edge bucket pass (NE/EB = 625 exact)
#define ENB 625

static inline int cdiv(int a, int b){ return (a+b-1)/b; }

// ======================= edge bucket pass (6-bit digit @ shift=11) =======================
// also zeroes indeg (needed by escatter6's embedded degree count, 2 dispatches later)
__global__ void k_ehist6(const int* __restrict__ key, int* __restrict__ hist, int shift,
                         int* __restrict__ indeg){
  for (int i = blockIdx.x*blockDim.x + threadIdx.x; i < NN0; i += gridDim.x*blockDim.x)
    indeg[i] = 0;
  __shared__ int lh[64];
  if (threadIdx.x < 64) lh[threadIdx.x] = 0;
  __syncthreads();
  int base = blockIdx.x*EB + threadIdx.x;
  #pragma unroll
  for (int u = 0; u < 8; u++)
    atomicAdd(&lh[(key[base + u*256] >> shift) & 63], 1);
  __syncthreads();
  if (threadIdx.x < 64) hist[threadIdx.x*ENB + blockIdx.x] = lh[threadIdx.x];
}

__global__ void k_scan_part(const int* __restrict__ in, int* __restrict__ bsum, int n){
  __shared__ int ws[256];
  int base = blockIdx.x*2048 + threadIdx.x*8;
  int s = 0;
  #pragma unroll
  for (int u = 0; u < 8; u++){ int i = base+u; if (i < n) s += in[i]; }
  ws[threadIdx.x] = s; __syncthreads();
  for (int st = 128; st > 0; st >>= 1){
    if (threadIdx.x < st) ws[threadIdx.x] += ws[threadIdx.x+st];
    __syncthreads();
  }
  if (threadIdx.x == 0) bsum[blockIdx.x] = ws[0];
}

__global__ void k_scan_fin_flat(int* __restrict__ data, const int* __restrict__ bsum, int nb, int n){
  __shared__ int bws[256]; __shared__ int ws[256];
  int t = threadIdx.x;
  bws[t] = (t < nb) ? bsum[t] : 0; __syncthreads();
  for (int st = 1; st < 256; st <<= 1){
    int a = (t >= st) ? bws[t-st] : 0; __syncthreads();
    bws[t] += a; __syncthreads();
  }
  int blockoff = (blockIdx.x == 0) ? 0 : bws[blockIdx.x-1];
  int base = blockIdx.x*2048 + t*8;
  int v[8]; int s = 0;
  #pragma unroll
  for (int u = 0; u < 8; u++){ int i = base+u; v[u] = (i < n) ? data[i] : 0; s += v[u]; }
  ws[t] = s; __syncthreads();
  for (int st = 1; st < 256; st <<= 1){
    int a = (t >= st) ? ws[t-st] : 0; __syncthreads();
    ws[t] += a; __syncthreads();
  }
  int off = blockoff + ws[t] - s;
  #pragma unroll
  for (int u = 0; u < 8; u++){
    int i = base+u;
    if (i < n){ data[i] = off; off += v[u]; }
  }
}

// bucket scatter + embedded degree count (random-target atomics — proven cheap r5/r7)
__global__ void k_escatter6(const int* __restrict__ keyin, const int* __restrict__ valin,
                            int* __restrict__ keyout, int* __restrict__ valout,
                            const int* __restrict__ hist, int shift,
                            int* __restrict__ indeg){
  __shared__ int dbase[64], run[64], wcnt[4][64];
  int t = threadIdx.x, lane = t & 63, w = t >> 6;
  if (t < 64){ dbase[t] = hist[t*ENB + blockIdx.x]; run[t] = 0; }
  __syncthreads();
  for (int u = 0; u < 8; u++){
    if (t < 64){ wcnt[0][t]=0; wcnt[1][t]=0; wcnt[2][t]=0; wcnt[3][t]=0; }
    __syncthreads();
    int g = blockIdx.x*EB + u*256 + t;
    int kk = keyin[g], vv = valin[g];
    int d = (kk >> shift) & 63;
    unsigned long long m = ~0ull;
    #pragma unroll
    for (int b = 0; b < 6; b++){
      unsigned long long bal = __ballot((d >> b) & 1);
      m &= ((d >> b) & 1) ? bal : ~bal;
    }
    int rnk = __popcll(m & ((1ull << lane) - 1ull));
    if (rnk == 0) wcnt[w][d] = __popcll(m);
    __syncthreads();
    int off2 = run[d] + rnk;
    for (int w2 = 0; w2 < w; w2++) off2 += wcnt[w2][d];
    int pos = dbase[d] + off2;
    keyout[pos] = kk; valout[pos] = vv;
    atomicAdd(&indeg[kk], 1);
    __syncthreads();
    if (t < 64) run[t] += wcnt[0][t] + wcnt[1][t] + wcnt[2][t] + wcnt[3][t];
    __syncthreads();
  }
}

// col scatter from bucketed edges: cursor atomics; writes stay in per-bucket windows
__global__ void k_escat_local(const int* __restrict__ ek, const int* __restrict__ ev,
                              int* __restrict__ cur, int* __restrict__ col){
  for (int e = blockIdx.x*blockDim.x + threadIdx.x; e < NE; e += gridDim.x*blockDim.x){
    int d = ek[e];
    int pos = atomicAdd(&cur[d], 1);
    col[pos] = ev[e];
  }
}

// ======================= fused single-dispatch scan =======================
__global__ void k_scan_rp(const int* __restrict__ in, int* __restrict__ rp,
                          int* __restrict__ cur, float* __restrict__ dA,
                          float* __restrict__ dB, int n){
  __shared__ int ws[256];
  int t = threadIdx.x;
  int pre = blockIdx.x*2048;
  int s = 0;
  for (int i = t; i < pre; i += 256) s += in[i];
  ws[t] = s; __syncthreads();
  for (int st = 128; st > 0; st >>= 1){
    if (t < st) ws[t] += ws[t+st];
    __syncthreads();
  }
  int blockoff = ws[0];
  __syncthreads();
  int base = pre + t*8;
  int v[8]; int ls = 0;
  #pragma unroll
  for (int u = 0; u < 8; u++){ int i = base+u; v[u] = (i < n) ? in[i] : 0; ls += v[u]; }
  ws[t] = ls; __syncthreads();
  for (int st = 1; st < 256; st <<= 1){
    int a = (t >= st) ? ws[t-st] : 0; __syncthreads();
    ws[t] += a; __syncthreads();
  }
  int off = blockoff + ws[t] - ls;
  #pragma unroll
  for (int u = 0; u < 8; u++){
    int i = base+u;
    if (i < n){
      rp[i] = off;
      if (cur) cur[i] = off;
      off += v[u];
      dA[i] = 1.0f/sqrtf((float)v[u] + 2.f);
      if (dB) dB[i] = 1.0f/sqrtf((float)v[u] + 1.f);
      if (i == n-1) rp[n] = off;
    }
  }
}

// ======================= convs (gather + matmul + BN partials) =======================
__global__ void k_conv64(const int* __restrict__ rp, const int* __restrict__ col,
                         const float* __restrict__ dinv, const float* __restrict__ x,
                         const float* __restrict__ W, float* __restrict__ out,
                         float* __restrict__ part, int n){
  __shared__ float yl[4][64];
  __shared__ float ls[64], lq[64];
  int lane = threadIdx.x & 63, w = threadIdx.x >> 6;
  if (threadIdx.x < 64){ ls[threadIdx.x] = 0.f; lq[threadIdx.x] = 0.f; }
  __syncthreads();
  float sa = 0.f, sq = 0.f;
  int wid = blockIdx.x*4 + w, nw = gridDim.x*4;
  for (int i = wid; i < n; i += nw){
    int beg = rp[i], end = rp[i+1];
    float di = dinv[i];
    float y = 0.f;
    int j = beg;
    for (; j + 4 <= end; j += 4){
      int s0 = col[j], s1 = col[j+1], s2 = col[j+2], s3 = col[j+3];
      float y0 = dinv[s0]*x[s0*64+lane];
      float y1 = dinv[s1]*x[s1*64+lane];
      float y2 = dinv[s2]*x[s2*64+lane];
      float y3 = dinv[s3]*x[s3*64+lane];
      y += (y0+y1) + (y2+y3);
    }
    for (; j < end; j++){ int s = col[j]; y += dinv[s]*x[s*64+lane]; }
    y = di*y + 2.f*di*di*x[i*64+lane];
    yl[w][lane] = y;
    float acc = 0.f;
    #pragma unroll
    for (int k2 = 0; k2 < 64; k2++)
      acc += yl[w][k2]*W[k2*64+lane];
    out[i*64+lane] = acc;
    sa += acc; sq += acc*acc;
  }
  atomicAdd(&ls[lane], sa); atomicAdd(&lq[lane], sq);
  __syncthreads();
  if (threadIdx.x < 128)
    part[blockIdx.x*128 + threadIdx.x] =
      (threadIdx.x < 64) ? ls[threadIdx.x] : lq[threadIdx.x-64];
}

__global__ void k_conv3(const int* __restrict__ rp, const int* __restrict__ col,
                        const float* __restrict__ dinv, const float* __restrict__ x,
                        const float* __restrict__ W, float* __restrict__ out,
                        float* __restrict__ part, int n){
  __shared__ float ls[64], lq[64];
  int lane = threadIdx.x & 63, w = threadIdx.x >> 6;
  if (threadIdx.x < 64){ ls[threadIdx.x] = 0.f; lq[threadIdx.x] = 0.f; }
  __syncthreads();
  float wf0 = W[lane], wf1 = W[64+lane], wf2 = W[128+lane];
  float sa = 0.f, sq = 0.f;
  int wid = blockIdx.x*4 + w, nw = gridDim.x*4;
  for (int i = wid; i < n; i += nw){
    int beg = rp[i], end = rp[i+1];
    float a0 = 0.f, a1 = 0.f, a2 = 0.f;
    for (int j = beg + lane; j < end; j += 64){
      int s2 = col[j];
      float ds = dinv[s2];
      a0 += ds*x[s2*3+0]; a1 += ds*x[s2*3+1]; a2 += ds*x[s2*3+2];
    }
    for (int o = 32; o > 0; o >>= 1){
      a0 += __shfl_xor(a0, o); a1 += __shfl_xor(a1, o); a2 += __shfl_xor(a2, o);
    }
    float di = dinv[i];
    float sl = 2.f*di*di;
    a0 = di*a0 + sl*x[i*3+0];
    a1 = di*a1 + sl*x[i*3+1];
    a2 = di*a2 + sl*x[i*3+2];
    float s = a0*wf0 + a1*wf1 + a2*wf2;
    out[i*64+lane] = s; sa += s; sq += s*s;
  }
  atomicAdd(&ls[lane], sa); atomicAdd(&lq[lane], sq);
  __syncthreads();
  if (threadIdx.x < 128)
    part[blockIdx.x*128 + threadIdx.x] =
      (threadIdx.x < 64) ? ls[threadIdx.x] : lq[threadIdx.x-64];
}

__global__ void k_stats_reduce(const float* __restrict__ part, float* __restrict__ stats, int nb){
  int c = blockIdx.x, lane = threadIdx.x;
  float s = 0.f;
  for (int b = lane; b < nb; b += 64) s += part[b*128 + c];
  for (int o = 32; o > 0; o >>= 1) s += __shfl_xor(s, o);
  if (lane == 0) stats[c] = s;
}

// ======================= pool: BN+ReLU (in-place) + score + key init =================
// r6-proven grid-stride wave-per-node structure (high occupancy).
__global__ void k_bnrelu_score(float* __restrict__ x, const float* __restrict__ stats,
                               const float* __restrict__ gamma, const float* __restrict__ beta,
                               const float* __restrict__ pw,
                               float* __restrict__ score, unsigned* __restrict__ key,
                               int* __restrict__ idx, int n, int P){
  int lane = threadIdx.x & 63, w = threadIdx.x >> 6;
  int wid = blockIdx.x*4 + w, nw = gridDim.x*4;
  float inv_n = 1.f/(float)n;
  float mu = stats[lane]*inv_n;
  float var = stats[64+lane]*inv_n - mu*mu;
  float gs = gamma[lane]*(1.f/sqrtf(var+1e-5f));
  float bt = beta[lane];
  float pv = pw[lane];
  float q = pv*pv;
  for (int o = 32; o > 0; o >>= 1) q += __shfl_xor(q, o);
  float qn = 1.f/sqrtf(q);
  for (int i = wid; i < n; i += nw){
    float v = fmaxf(gs*(x[i*64+lane]-mu)+bt, 0.f);
    x[i*64+lane] = v;
    float s = v*pv;
    for (int o = 32; o > 0; o >>= 1) s += __shfl_xor(s, o);
    if (lane == 0){
      float sc = fmaxf(s*qn, 0.f);
      score[i] = sc; key[i] = ~__float_as_uint(sc); idx[i] = i;
    }
  }
  for (int g = n + wid; g < P; g += nw)
    if (lane == 0){ key[g] = 0xFFFFFFFFu; idx[g] = 0; }
}

// ======================= score radix sort (8-bit LDS hist, stable, exact) ============
__global__ void k_radix_hist(const unsigned* __restrict__ key, int* __restrict__ hist,
                             int shift, int nblk){
  __shared__ int lh[256];
  lh[threadIdx.x] = 0; __syncthreads();
  int base = blockIdx.x*1024 + threadIdx.x;
  #pragma unroll
  for (int u = 0; u < 4; u++){
    unsigned d = (key[base + u*256] >> shift) & 255u;
    atomicAdd(&lh[d], 1);
  }
  __syncthreads();
  hist[threadIdx.x*nblk + blockIdx.x] = lh[threadIdx.x];
}

// stable scatter; fin=1 (last pass) writes perm/mapv/xk directly (validated r7, absmax 0.0)
__global__ void k_radix_scatter(const unsigned* __restrict__ keyin, const int* __restrict__ idxin,
                                unsigned* __restrict__ keyout, int* __restrict__ idxout,
                                const int* __restrict__ hist, int shift, int nblk,
                                int fin, const float* __restrict__ x,
                                const float* __restrict__ score,
                                int* __restrict__ perm, int* __restrict__ mapv,
                                float* __restrict__ xk, int n, int k){
  __shared__ int dbase[256], run[256], sc[256];
  __shared__ int wcnt[4][256];
  int t = threadIdx.x, lane = t & 63, w = t >> 6;
  int pre = 0, tot = 0;
  for (int b = 0; b < nblk; b++){
    int v = hist[t*nblk + b];
    if (b < blockIdx.x) pre += v;
    tot += v;
  }
  sc[t] = tot; __syncthreads();
  for (int st = 1; st < 256; st <<= 1){
    int a = (t >= st) ? sc[t-st] : 0; __syncthreads();
    sc[t] += a; __syncthreads();
  }
  dbase[t] = sc[t] - tot + pre;
  run[t] = 0;
  for (int u = 0; u < 4; u++){
    wcnt[0][t] = 0; wcnt[1][t] = 0; wcnt[2][t] = 0; wcnt[3][t] = 0;
    __syncthreads();
    int g = blockIdx.x*1024 + u*256 + t;
    unsigned kk = keyin[g]; int id = idxin[g];
    unsigned d = (kk >> shift) & 255u;
    unsigned long long m = ~0ull;
    #pragma unroll
    for (int b = 0; b < 8; b++){
      unsigned long long bal = __ballot((d >> b) & 1u);
      m &= ((d >> b) & 1u) ? bal : ~bal;
    }
    int rnk = __popcll(m & ((1ull << lane) - 1ull));
    if (rnk == 0) wcnt[w][d] = __popcll(m);
    __syncthreads();
    int off2 = run[d] + rnk;
    for (int w2 = 0; w2 < w; w2++) off2 += wcnt[w2][d];
    int pos = dbase[d] + off2;
    if (!fin){
      keyout[pos] = kk; idxout[pos] = id;
    } else if (pos < n){
      mapv[id] = (pos < k) ? pos : -1;
      if (pos < k){
        perm[pos] = id;
        float scv = score[id];
        const float4* xr = (const float4*)(x + (size_t)id*64);
        float4* xo = (float4*)(xk + (size_t)pos*64);
        #pragma unroll
        for (int f = 0; f < 16; f++){
          float4 vv = xr[f];
          vv.x *= scv; vv.y *= scv; vv.z *= scv; vv.w *= scv;
          xo[f] = vv;
        }
      }
    }
    __syncthreads();
    run[t] += wcnt[0][t] + wcnt[1][t] + wcnt[2][t] + wcnt[3][t];
    __syncthreads();
  }
}

// ======================= child CSR from parent CSR + injective mapping ================
__global__ void k_hist_mapped(const int* __restrict__ rp_p, const int* __restrict__ col_p,
                              const int* __restrict__ mapv, int* __restrict__ indeg, int np){
  int d = blockIdx.x*blockDim.x + threadIdx.x;
  if (d >= np) return;
  int md = mapv[d];
  if (md < 0) return;
  int c = 0, e = rp_p[d+1];
  int j = rp_p[d];
  for (; j + 4 <= e; j += 4){
    int c0 = (mapv[col_p[j]]   >= 0);
    int c1 = (mapv[col_p[j+1]] >= 0);
    int c2 = (mapv[col_p[j+2]] >= 0);
    int c3 = (mapv[col_p[j+3]] >= 0);
    c += (c0+c1) + (c2+c3);
  }
  for (; j < e; j++) if (mapv[col_p[j]] >= 0) c++;
  indeg[md] = c;
}

__global__ void k_scatter_mapped(const int* __restrict__ rp_p, const int* __restrict__ col_p,
                                 const int* __restrict__ mapv, const int* __restrict__ rp_c,
                                 int* __restrict__ col_c, int np){
  int d = blockIdx.x*blockDim.x + threadIdx.x;
  if (d >= np) return;
  int md = mapv[d];
  if (md < 0) return;
  int pos = rp_c[md], e = rp_p[d+1];
  int j = rp_p[d];
  for (; j + 4 <= e; j += 4){
    int m0 = mapv[col_p[j]], m1 = mapv[col_p[j+1]];
    int m2 = mapv[col_p[j+2]], m3 = mapv[col_p[j+3]];
    if (m0 >= 0) col_c[pos++] = m0;
    if (m1 >= 0) col_c[pos++] = m1;
    if (m2 >= 0) col_c[pos++] = m2;
    if (m3 >= 0) col_c[pos++] = m3;
  }
  for (; j < e; j++){
    int ms = mapv[col_p[j]];
    if (ms >= 0) col_c[pos++] = ms;
  }
}

// ======================= up-path BN+ReLU + scatter-add =======================
__global__ void k_bnrelu_scatter(const float* __restrict__ x, const float* __restrict__ stats,
                                 const float* __restrict__ gamma, const float* __restrict__ beta,
                                 const int* __restrict__ perm, float* __restrict__ res, int n){
  int t = blockIdx.x*blockDim.x + threadIdx.x;
  if (t >= n*64) return;
  int r = t >> 6, f = t & 63;
  float inv_n = 1.0f/(float)n;
  float mu = stats[f]*inv_n;
  float var = stats[64+f]*inv_n - mu*mu;
  float v = gamma[f]*(x[t]-mu)*(1.0f/sqrtf(var+1e-5f)) + beta[f];
  res[perm[r]*64+f] += fmaxf(v, 0.f);
}

// ======================= final conv =======================
__global__ void k_matvec(const float* __restrict__ x, const float* __restrict__ W,
                         float* __restrict__ h1, int n){
  int lane = threadIdx.x & 63, w = threadIdx.x >> 6;
  int wid = blockIdx.x*4 + w, nw = gridDim.x*4;
  float wv = W[lane];
  for (int i = wid; i < n; i += nw){
    float v = x[i*64+lane]*wv;
    for (int o = 32; o > 0; o >>= 1) v += __shfl_xor(v, o);
    if (lane == 0) h1[i] = v;
  }
}

__global__ void k_gather_sig(const int* __restrict__ rp, const int* __restrict__ col,
                             const float* __restrict__ dinv, const float* __restrict__ h1,
                             float* __restrict__ out, int n){
  int i = blockIdx.x*blockDim.x + threadIdx.x;
  if (i >= n) return;
  int beg = rp[i], end = rp[i+1];
  float di = dinv[i];
  float acc = 0.f;
  int j = beg;
  for (; j + 4 <= end; j += 4){
    int s0 = col[j], s1 = col[j+1], s2 = col[j+2], s3 = col[j+3];
    float v0 = dinv[s0]*h1[s0];
    float v1 = dinv[s1]*h1[s1];
    float v2 = dinv[s2]*h1[s2];
    float v3 = dinv[s3]*h1[s3];
    acc += (v0+v1) + (v2+v3);
  }
  for (; j < end; j++) acc += dinv[col[j]]*h1[col[j]];
  float v = di*acc + di*di*h1[i];
  out[i] = 1.f/(1.f+expf(-v));
}

// ======================= host =======================

extern "C" void kernel_launch(void* const* d_in, const int* in_sizes, int n_in,
                              void* d_out, int out_size, void* d_ws, size_t ws_size,
                              hipStream_t stream) {
  const float* x_in = (const float*)d_in[0];
  const int* ei = (const int*)d_in[1];
  const int* src0 = ei;
  const int* dst0 = ei + NE;
  const float* W_d[4] = {(const float*)d_in[2],(const float*)d_in[5],(const float*)d_in[8],(const float*)d_in[11]};
  const float* g_d[4] = {(const float*)d_in[3],(const float*)d_in[6],(const float*)d_in[9],(const float*)d_in[12]};
  const float* b_d[4] = {(const float*)d_in[4],(const float*)d_in[7],(const float*)d_in[10],(const float*)d_in[13]};
  const float* pw[3]  = {(const float*)d_in[14],(const float*)d_in[15],(const float*)d_in[16]};
  const float* W_u[2] = {(const float*)d_in[17],(const float*)d_in[20]};
  const float* g_u[2] = {(const float*)d_in[18],(const float*)d_in[21]};
  const float* b_u[2] = {(const float*)d_in[19],(const float*)d_in[22]};
  const float* W_out  = (const float*)d_in[23];
  float* out = (float*)d_out;

  float* base = (float*)d_ws;
  size_t off = 0;
  auto alloc = [&](size_t nf){ float* p = base + off; off += nf; return p; };
  float* x0 = alloc(5120000);
  float* x1 = alloc(2560000);
  float* x2 = alloc(1280000);
  float* x3 = alloc(640000);
  float* A  = alloc(2560000);
  int* col0 = (int*)alloc(NE);
  int* col1 = (int*)alloc(NE);
  int* col2 = (int*)alloc(NE);
  int* col3 = (int*)alloc(NE);
  int* ek1 = (int*)alloc(NE);
  int* ev1 = (int*)alloc(NE);
  int* rp0 = (int*)alloc(80001);
  int* rp1 = (int*)alloc(40001);
  int* rp2 = (int*)alloc(20001);
  int* rp3 = (int*)alloc(10001);
  int* cur0 = (int*)alloc(NN0);
  int* indeg  = (int*)alloc(NN0);
  float* dinv0  = alloc(NN0);
  float* dinv0f = alloc(NN0);
  float* dinv1  = alloc(40000);
  float* dinv2  = alloc(20000);
  float* dinv3  = alloc(10000);
  float* score = alloc(NN0);
  int* mapv = (int*)alloc(NN0);
  int* p0 = (int*)alloc(40000);
  int* p1 = (int*)alloc(20000);
  int* p2 = (int*)alloc(10000);
  float* stats = alloc(128);
  float* part  = alloc(2048*128);
  unsigned* keyA = (unsigned*)alloc(81920);
  unsigned* keyB = (unsigned*)alloc(81920);
  int* idxA = (int*)alloc(81920);
  int* idxB = (int*)alloc(81920);
  int* hist = (int*)alloc(81920);
  int* ehist = (int*)alloc(64*ENB);
  int* bsum = (int*)alloc(256);
  (void)ws_size; (void)in_sizes; (void)n_in; (void)out_size;

  const int B = 256;

  // ---- level-0 CSR: bucket scatter (+deg) + fused scan + local col scatter ----
  k_ehist6<<<ENB, B, 0, stream>>>(dst0, ehist, 11, indeg);
  {
    int nb = cdiv(64*ENB, 2048);
    k_scan_part    <<<nb, B, 0, stream>>>(ehist, bsum, 64*ENB);
    k_scan_fin_flat<<<nb, B, 0, stream>>>(ehist, bsum, nb, 64*ENB);
  }
  k_escatter6<<<ENB, B, 0, stream>>>(dst0, src0, ek1, ev1, ehist, 11, indeg);
  k_scan_rp<<<cdiv(NN0,2048), B, 0, stream>>>(indeg, rp0, cur0, dinv0, dinv0f, NN0);
  k_escat_local<<<1024, B, 0, stream>>>(ek1, ev1, cur0, col0);

  auto conv = [&](const float* xin, const float* W, int n, int nb,
                  const int* rp, const int* col, const float* dv, float* dstb){
    k_conv64<<<nb, B, 0, stream>>>(rp, col, dv, xin, W, dstb, part, n);
    k_stats_reduce<<<128, 64, 0, stream>>>(part, stats, nb);
  };

  auto pool = [&](float* xb, const float* gm, const float* bt, const float* pwv,
                  int n, int k, int* pm){
    int nblk = cdiv(n, 1024), P = nblk*1024;
    k_bnrelu_score<<<1024, B, 0, stream>>>(xb, stats, gm, bt, pwv, score, keyA, idxA, n, P);
    // pass 0..2: plain stable scatters; pass 3: fin (writes perm/mapv/xk)
    k_radix_hist   <<<nblk, B, 0, stream>>>(keyA, hist, 0, nblk);
    k_radix_scatter<<<nblk, B, 0, stream>>>(keyA, idxA, keyB, idxB, hist, 0, nblk,
                                            0, nullptr, nullptr, nullptr, nullptr, nullptr, n, k);
    k_radix_hist   <<<nblk, B, 0, stream>>>(keyB, hist, 8, nblk);
    k_radix_scatter<<<nblk, B, 0, stream>>>(keyB, idxB, keyA, idxA, hist, 8, nblk,
                                            0, nullptr, nullptr, nullptr, nullptr, nullptr, n, k);
    k_radix_hist   <<<nblk, B, 0, stream>>>(keyA, hist, 16, nblk);
    k_radix_scatter<<<nblk, B, 0, stream>>>(keyA, idxA, keyB, idxB, hist, 16, nblk,
                                            0, nullptr, nullptr, nullptr, nullptr, nullptr, n, k);
    k_radix_hist   <<<nblk, B, 0, stream>>>(keyB, hist, 24, nblk);
    k_radix_scatter<<<nblk, B, 0, stream>>>(keyB, idxB, keyA, idxA, hist, 24, nblk,
                                            1, xb, score, pm, mapv, A, n, k);
  };

  auto csr_mapped = [&](const int* rp_p, const int* col_p, int np, int nc,
                        int* rp_c, int* col_c, float* dv){
    k_hist_mapped<<<cdiv(np,B), B, 0, stream>>>(rp_p, col_p, mapv, indeg, np);
    k_scan_rp<<<cdiv(nc,2048), B, 0, stream>>>(indeg, rp_c, nullptr, dv, nullptr, nc);
    k_scatter_mapped<<<cdiv(np,B), B, 0, stream>>>(rp_p, col_p, mapv, rp_c, col_c, np);
  };

  // ---- down path ----
  k_conv3<<<2048, B, 0, stream>>>(rp0, col0, dinv0, x_in, W_d[0], x0, part, NN0);
  k_stats_reduce<<<128, 64, 0, stream>>>(part, stats, 2048);
  pool(x0, g_d[0], b_d[0], pw[0], NN0, 40000, p0);
  csr_mapped(rp0, col0, NN0, 40000, rp1, col1, dinv1);

  conv(A, W_d[1], 40000, 2048, rp1, col1, dinv1, x1);
  pool(x1, g_d[1], b_d[1], pw[1], 40000, 20000, p1);
  csr_mapped(rp1, col1, 40000, 20000, rp2, col2, dinv2);

  conv(A, W_d[2], 20000, 1024, rp2, col2, dinv2, x2);
  pool(x2, g_d[2], b_d[2], pw[2], 20000, 10000, p2);
  csr_mapped(rp2, col2, 20000, 10000, rp3, col3, dinv3);

  conv(A, W_d[3], 10000, 512, rp3, col3, dinv3, x3);

  // ---- up path (BN+ReLU fused into the skip-connection scatter-add) ----
  k_bnrelu_scatter<<<cdiv(10000*64,B), B, 0, stream>>>(x3, stats, g_d[3], b_d[3], p2, x2, 10000);
  conv(x2, W_u[0], 20000, 1024, rp2, col2, dinv2, A);
  k_bnrelu_scatter<<<cdiv(20000*64,B), B, 0, stream>>>(A, stats, g_u[0], b_u[0], p1, x1, 20000);
  conv(x1, W_u[1], 40000, 2048, rp1, col1, dinv1, A);
  k_bnrelu_scatter<<<cdiv(40000*64,B), B, 0, stream>>>(A, stats, g_u[1], b_u[1], p0, x0, 40000);

  // ---- final conv (fill = 1.0) fused with sigmoid ----
  float* h1 = score;  // reuse
  k_matvec<<<512, B, 0, stream>>>(x0, W_out, h1, NN0);
  k_gather_sig<<<cdiv(NN0,B), B, 0, stream>>>(rp0, col0, dinv0f, h1, out, NN0);
}